// Round 4
// baseline (346.808 us; speedup 1.0000x reference)
//
#include <hip/hip_runtime.h>
#include <math.h>

#define NB 96
#define NB2 (NB * NB)
#define DFEAT 64
#define NCLS 21
#define MARGIN 0.3
#define JPB 4                  // j values per block
#define NJB (NB / JPB)         // 24 j-groups
#define NBLK (NB * NJB)        // 2304 blocks

typedef int i4 __attribute__((ext_vector_type(4)));

// ---------------------------------------------------------------------------
// One block per (i, j-quad). 384 threads (6 waves).
//
// valid[i,j,k,n] = sames[i,j] & sames[i,k] & (j<k) & diffs[i,n]
//                  & (mat[i,n] <= MARGIN + max(mat[i,j], mat[i,k]))
//
// Key identity: smat[n] <= max(thr_j, thr_k)  <=>
//               (smat[n] <= thr_j) | (smat[n] <= thr_k)
// so all f64 compares collapse into a 96x96 bit matrix computed ONCE per
// block; the streaming loop is pure int ops (1 LDS broadcast + 4 bfe per
// int4 store) with zero branches -- rows failing the (sames/j<k) gate are
// zero words in the table.
//
// Phase 1 : row i of smat/sthr/svalid (f64, bit-identical to prior rounds).
// Phase 1b: bits[k][w] (w=0..2): bit b of word w = (smat[32w+b] <= sthr[k]).
// Phase 1c: gw[j'][k][w] = gate(i,j,k) ? bits[j][w] | bits[k][w] : 0.
// Epilogue: 4 j-rows x 96 k-rows of int4 chunks; wave writes contiguous 1KB.
// ---------------------------------------------------------------------------
__global__ __launch_bounds__(384) void fused_quad_kernel(
    const float* __restrict__ logits,
    const float* __restrict__ labels,
    const float* __restrict__ feat2,
    int* __restrict__ out) {
  const int bid = blockIdx.x;
  const int i = bid / NJB;
  const int j4 = (bid - i * NJB) * JPB;
  const int tid = threadIdx.x;

  __shared__ double smat[NB];            // diffs[i,n] ? mat[i,n] : +inf
  __shared__ double sthr[NB];            // MARGIN + mat[i,n]
  __shared__ unsigned char svalid[NB];   // sames[i,n]
  __shared__ unsigned int bits[NB][3];   // per-k 96-bit compare mask
  __shared__ unsigned int gw[JPB][NB][3];// gated OR'd output words

  // ---- phase 1: row i of mat/thr/share, 4 threads per n --------------------
  {
    const int n = tid >> 2;   // 0..95
    const int l4 = tid & 3;   // 0..3 (aligned quad within a wave)
    const float* xi = logits + i * DFEAT + l4 * 16;
    const float* yn = feat2 + n * DFEAT + l4 * 16;
    double dot = 0.0, nx = 0.0, ny = 0.0;
#pragma unroll
    for (int d = 0; d < 16; ++d) {
      double a = (double)xi[d];
      double b = (double)yn[d];
      dot += a * b;
      nx += a * a;
      ny += b * b;
    }
    dot += __shfl_xor(dot, 1); nx += __shfl_xor(nx, 1); ny += __shfl_xor(ny, 1);
    dot += __shfl_xor(dot, 2); nx += __shfl_xor(nx, 2); ny += __shfl_xor(ny, 2);
    if (l4 == 0) {
      nx = fmax(sqrt(nx), 1e-12);
      ny = fmax(sqrt(ny), 1e-12);
      double m = -(dot / (nx * ny));
      // labels are exact 0.0/1.0 so the f32 dot is an exact count
      const float* li = labels + i * NCLS;
      const float* ln = labels + n * NCLS;
      float ld = 0.f;
#pragma unroll
      for (int c = 0; c < NCLS; ++c) ld += li[c] * ln[c];
      const bool share = (ld > 0.f);
      smat[n] = share ? 1e300 : m;  // diagonal NOT excluded from diffs (ref)
      sthr[n] = MARGIN + m;
      svalid[n] = (share && n != i) ? 1 : 0;
    }
  }
  __syncthreads();

  // ---- phase 1b: 96x96 compare-bit matrix, one (k, word) per thread --------
  if (tid < NB * 3) {
    const int k = tid / 3;
    const int w = tid - 3 * k;
    const double t = sthr[k];
    unsigned int m = 0u;
#pragma unroll
    for (int b = 0; b < 32; ++b)
      m |= (smat[w * 32 + b] <= t) ? (1u << b) : 0u;
    bits[k][w] = m;
  }
  __syncthreads();

  // ---- phase 1c: gated OR words for the 4 j-values -------------------------
  // JPB*NB*3 = 1152 = 3 * 384 -> exactly 3 uniform iterations
#pragma unroll
  for (int s = 0; s < 3; ++s) {
    const int u = tid + s * 384;
    const int jj = u / (NB * 3);
    const int rem = u - jj * (NB * 3);
    const int k = rem / 3;
    const int w = rem - 3 * k;
    const int j = j4 + jj;
    const bool gate = svalid[j] && svalid[k] && (j < k);
    gw[jj][k][w] = gate ? (bits[j][w] | bits[k][w]) : 0u;
  }
  __syncthreads();

  // ---- epilogue: pure int bit-extract store stream -------------------------
  const int q = tid % 24;        // n-chunk (0..23), fixed per thread
  const int kr = tid / 24;       // k residue (0..15)
  const int wi = q >> 3;         // which 32-bit word holds bits 4q..4q+3
  const int bb = (q & 7) * 4;    // bit base within that word
  i4* outp = (i4*)(out + (size_t)(i * NB + j4) * (size_t)NB2);

#pragma unroll
  for (int jj = 0; jj < JPB; ++jj) {
#pragma unroll
    for (int r = 0; r < 6; ++r) {
      const int k = 16 * r + kr;
      const unsigned int wv = gw[jj][k][wi];
      i4 v;
      v.x = (int)((wv >> bb) & 1u);
      v.y = (int)((wv >> (bb + 1)) & 1u);
      v.z = (int)((wv >> (bb + 2)) & 1u);
      v.w = (int)((wv >> (bb + 3)) & 1u);
      outp[jj * (NB2 / 4) + k * 24 + q] = v;
    }
  }
}

extern "C" void kernel_launch(void* const* d_in, const int* in_sizes, int n_in,
                              void* d_out, int out_size, void* d_ws, size_t ws_size,
                              hipStream_t stream) {
  const float* logits = (const float*)d_in[0];  // [96,64]
  const float* labels = (const float*)d_in[1];  // [96,21]
  const float* feat2  = (const float*)d_in[2];  // [96,64]
  int* out = (int*)d_out;                       // [96,96,96,96] as 0/1 int32

  fused_quad_kernel<<<NBLK, 384, 0, stream>>>(logits, labels, feat2, out);
}

// Round 5
// 341.414 us; speedup vs baseline: 1.0158x; 1.0158x over previous
//
#include <hip/hip_runtime.h>
#include <math.h>

#define NB 96
#define NB2 (NB * NB)
#define DFEAT 64
#define NCLS 21
#define MARGIN 0.3

typedef int i4 __attribute__((ext_vector_type(4)));

// ---------------------------------------------------------------------------
// valid[i,j,k,n] = sames[i,j] & sames[i,k] & (j<k) & diffs[i,n]
//                  & (mat[i,n] <= MARGIN + max(mat[i,j], mat[i,k]))
// and  smat[n] <= max(t_j,t_k)  <=>  (smat[n] <= t_j) | (smat[n] <= t_k).
//
// Kernel A (96 blocks, ~4 us): per i, compute row tables into workspace:
//   bitsT[(i*96+x)*3+w] : bit b of word w = (smat_i[32w+b] <= MARGIN+mat[i,x])
//   svalT[i*96+x]       : sames[i,x]  (share && x!=i)
// f64 math identical to all previous passing rounds (absmax 0).
//
// Kernel B (fill-like streamer): zero LDS, zero barriers, zero f64, no
// block phases. Grid-stride over flat int4 index f; lanes store consecutive
// 16B (perfectly coalesced); value = branchless 2-byte + 2-word lookup from
// the ~117 KB L1/L2-resident tables. This is as close to
// __amd_rocclr_fillBufferAligned's structure as a compute kernel gets --
// the decisive test of "block structure vs write-BW floor".
// ---------------------------------------------------------------------------

__global__ __launch_bounds__(384) void table_kernel(
    const float* __restrict__ logits,
    const float* __restrict__ labels,
    const float* __restrict__ feat2,
    unsigned int* __restrict__ bitsT,
    unsigned char* __restrict__ svalT) {
  const int i = blockIdx.x;
  const int tid = threadIdx.x;

  __shared__ double smat[NB];  // diffs[i,n] ? mat[i,n] : +inf
  __shared__ double sthr[NB];  // MARGIN + mat[i,n]

  {
    const int n = tid >> 2;   // 0..95
    const int l4 = tid & 3;   // 0..3
    const float* xi = logits + i * DFEAT + l4 * 16;
    const float* yn = feat2 + n * DFEAT + l4 * 16;
    double dot = 0.0, nx = 0.0, ny = 0.0;
#pragma unroll
    for (int d = 0; d < 16; ++d) {
      double a = (double)xi[d];
      double b = (double)yn[d];
      dot += a * b;
      nx += a * a;
      ny += b * b;
    }
    dot += __shfl_xor(dot, 1); nx += __shfl_xor(nx, 1); ny += __shfl_xor(ny, 1);
    dot += __shfl_xor(dot, 2); nx += __shfl_xor(nx, 2); ny += __shfl_xor(ny, 2);
    if (l4 == 0) {
      nx = fmax(sqrt(nx), 1e-12);
      ny = fmax(sqrt(ny), 1e-12);
      double m = -(dot / (nx * ny));
      // labels are exact 0.0/1.0 so the f32 dot is an exact count
      const float* li = labels + i * NCLS;
      const float* ln = labels + n * NCLS;
      float ld = 0.f;
#pragma unroll
      for (int c = 0; c < NCLS; ++c) ld += li[c] * ln[c];
      const bool share = (ld > 0.f);
      smat[n] = share ? 1e300 : m;  // diagonal NOT excluded from diffs (ref)
      sthr[n] = MARGIN + m;
      svalT[i * NB + n] = (share && n != i) ? 1 : 0;
    }
  }
  __syncthreads();

  if (tid < NB * 3) {
    const int x = tid / 3;
    const int w = tid - 3 * x;
    const double t = sthr[x];
    unsigned int m = 0u;
#pragma unroll
    for (int b = 0; b < 32; ++b)
      m |= (smat[w * 32 + b] <= t) ? (1u << b) : 0u;
    bitsT[(i * NB + x) * 3 + w] = m;
  }
}

// 96^3 rows * 24 int4-chunks per row = 21,233,664 int4 stores.
// 2592 blocks * 256 threads * 32 iters covers it exactly.
#define TOT4 (NB * NB2 * 24)
#define SBLK 2592

__global__ __launch_bounds__(256) void stream_kernel(
    const unsigned int* __restrict__ bitsT,
    const unsigned char* __restrict__ svalT,
    int* __restrict__ out) {
  const unsigned int stride = SBLK * 256;
  unsigned int f = blockIdx.x * 256 + threadIdx.x;
  i4* outp = (i4*)out;
#pragma unroll 4
  for (int it = 0; it < 32; ++it, f += stride) {
    const unsigned int row = f / 24u;      // (i*96+j)*96 + k
    const unsigned int q = f - row * 24u;  // n-chunk 0..23
    const unsigned int ij = row / 96u;     // i*96 + j
    const unsigned int k = row - ij * 96u;
    const unsigned int i = ij / 96u;
    const unsigned int j = ij - i * 96u;
    const unsigned int ik = ij - j + k;    // i*96 + k
    const unsigned int w = q >> 3;
    // branchless gate: svalT values are exactly 0/1
    const unsigned int g =
        (unsigned int)(svalT[ij] & svalT[ik]) & (unsigned int)(j < k);
    const unsigned int wv =
        (bitsT[ij * 3u + w] | bitsT[ik * 3u + w]) & (0u - g);
    const unsigned int bb = (q & 7u) * 4u;
    i4 v;
    v.x = (int)((wv >> bb) & 1u);
    v.y = (int)((wv >> (bb + 1u)) & 1u);
    v.z = (int)((wv >> (bb + 2u)) & 1u);
    v.w = (int)((wv >> (bb + 3u)) & 1u);
    __builtin_nontemporal_store(v, &outp[f]);
  }
}

extern "C" void kernel_launch(void* const* d_in, const int* in_sizes, int n_in,
                              void* d_out, int out_size, void* d_ws, size_t ws_size,
                              hipStream_t stream) {
  const float* logits = (const float*)d_in[0];  // [96,64]
  const float* labels = (const float*)d_in[1];  // [96,21]
  const float* feat2  = (const float*)d_in[2];  // [96,64]
  int* out = (int*)d_out;                       // [96,96,96,96] as 0/1 int32

  unsigned int* bitsT = (unsigned int*)d_ws;            // 96*96*3*4 = 110,592 B
  unsigned char* svalT = (unsigned char*)(bitsT + NB2 * 3);  // 9,216 B

  table_kernel<<<NB, 384, 0, stream>>>(logits, labels, feat2, bitsT, svalT);
  stream_kernel<<<SBLK, 256, 0, stream>>>(bitsT, svalT, out);
}